// Round 4
// baseline (354.575 us; speedup 1.0000x reference)
//
#include <hip/hip_runtime.h>

// ---------------------------------------------------------------------------
// LigerFusedNeighborhoodAttention on MI355X (gfx950)
// B=2, S=8192, H=1024, NH=16, HD=64, KERNEL=7, DILATION=1, SCALE=1/8
//
// Pipeline:
//   1. cast X fp32 -> bf16
//   2. transpose+cast weights -> bf16 (one z-indexed kernel)
//   3. fused QKV GEMM (16384 x 3072 x 1024), BK=64, swizzled staging,
//      L2-locality block swizzle, LDS-coalesced epilogues:
//        QK -> row-major bf16 (16B stores); V -> Vt (2,16,64,8192)
//   4. MFMA banded attention (unchanged, verified)
//   5. output GEMM (16384 x 1024 x 1024) -> d_out fp32 (16B stores)
// ---------------------------------------------------------------------------

typedef __bf16 bf16x8 __attribute__((ext_vector_type(8)));
typedef float f32x4 __attribute__((ext_vector_type(4)));
typedef int int4v __attribute__((ext_vector_type(4)));
typedef __attribute__((address_space(1))) void as1_void;
typedef __attribute__((address_space(3))) void as3_void;

__device__ __forceinline__ float bf2f(unsigned short u) {
    union { unsigned int u; float f; } c;
    c.u = ((unsigned int)u) << 16;
    return c.f;
}
__device__ __forceinline__ unsigned short f2bf(float f) {
    union { float f; unsigned int u; } c;
    c.f = f;
    unsigned int u = c.u;
    u += 0x7fffu + ((u >> 16) & 1u);   // round-to-nearest-even
    return (unsigned short)(u >> 16);
}

// --------------------------- cast X fp32 -> bf16 ---------------------------
__global__ __launch_bounds__(256) void cast_kernel(
    const float* __restrict__ in, unsigned short* __restrict__ out, int n4) {
    int i = blockIdx.x * 256 + threadIdx.x;
    if (i < n4) {
        float4 v = ((const float4*)in)[i];
        ushort4 o;
        o.x = f2bf(v.x); o.y = f2bf(v.y); o.z = f2bf(v.z); o.w = f2bf(v.w);
        ((ushort4*)out)[i] = o;
    }
}

// ----------- transpose+cast 4x (1024x1024) W -> Wt bf16, z-indexed ---------
__global__ __launch_bounds__(256) void transpose_cast4(
    const float* __restrict__ w0, const float* __restrict__ w1,
    const float* __restrict__ w2, const float* __restrict__ w3,
    unsigned short* __restrict__ t0, unsigned short* __restrict__ t3) {
    __shared__ unsigned short tile[32][33];
    const int z = blockIdx.z;
    const float* W = (z == 0) ? w0 : (z == 1) ? w1 : (z == 2) ? w2 : w3;
    unsigned short* Wt = (z == 3) ? t3 : t0 + (size_t)z * 1048576;
    const int c0 = blockIdx.x * 32;
    const int r0 = blockIdx.y * 32;
    const int tx = threadIdx.x & 31;
    const int ty = threadIdx.x >> 5;
#pragma unroll
    for (int i = 0; i < 32; i += 8)
        tile[ty + i][tx] = f2bf(W[(size_t)(r0 + ty + i) * 1024 + c0 + tx]);
    __syncthreads();
#pragma unroll
    for (int i = 0; i < 32; i += 8)
        Wt[(size_t)(c0 + ty + i) * 1024 + r0 + tx] = tile[tx][ty + i];
}

// --------------------------- bias concat (3072) ----------------------------
__global__ __launch_bounds__(256) void concat_bias(
    const float* __restrict__ a, const float* __restrict__ b,
    const float* __restrict__ c, float* __restrict__ o) {
    int i = blockIdx.x * 256 + threadIdx.x;
    if (i < 3072)
        o[i] = (i < 1024) ? a[i] : ((i < 2048) ? b[i - 1024] : c[i - 2048]);
}

// ------------------------------- MFMA GEMM ---------------------------------
// C(M,N) = A(M,K)*Bt(N,K)^T + bias.  BK=64, 128x128 tile, 4 waves.
// Block swizzle: 16 consecutive blocks share one B-tile (col-major in group).
// MODE 0: fp32 out, LDS-coalesced 16B stores.
// MODE 1: col<2048 -> QK bf16 row-major (16B stores); col>=2048 -> Vt.
template <int MODE>
__device__ __forceinline__ void gemm_body(
    const unsigned short* __restrict__ A, const unsigned short* __restrict__ Bt,
    const float* __restrict__ bias, float* __restrict__ Cf,
    unsigned short* __restrict__ Cb, unsigned short* __restrict__ Vt,
    int N, int K) {
    __shared__ unsigned short smem[16384];     // sA = [0:8192), sB = [8192:16384)
    const int tid = threadIdx.x;
    const int lane = tid & 63;
    const int wave = tid >> 6;

    // L2-locality swizzle: group of 16 row-tiles, col-major within group
    const int nbx = gridDim.x;
    const int n = blockIdx.y * nbx + blockIdx.x;
    const int per = nbx * 16;
    const int g = n / per;
    const int rm = n - g * per;
    const int bm = (g * 16 + (rm & 15)) * 128;
    const int bn = (rm >> 4) * 128;

    const int wm = (wave >> 1) * 64;
    const int wn = (wave & 1) * 64;
    const int quad = lane >> 4;
    const int mr = lane & 15;

    // staging chunk ids: q = (k*4+wave)*64 + lane, k=0..3 (covers 1024 chunks)
    const unsigned short* gA[4];
    const unsigned short* gB[4];
    char* lA[4];
    char* lB[4];
#pragma unroll
    for (int k = 0; k < 4; ++k) {
        const int q = (k * 4 + wave) * 64 + lane;
        const int row = q >> 3;
        const int c8 = (q & 7) ^ (row & 7);    // source-column swizzle
        gA[k] = A + (size_t)(bm + row) * K + c8 * 8;
        gB[k] = Bt + (size_t)(bn + row) * K + c8 * 8;
        lA[k] = (char*)smem + (size_t)(k * 4 + wave) * 1024;
        lB[k] = (char*)smem + 16384 + (size_t)(k * 4 + wave) * 1024;
    }

    f32x4 acc[4][4] = {};

    for (int kt = 0; kt < K; kt += 64) {
#pragma unroll
        for (int k = 0; k < 4; ++k) {
            __builtin_amdgcn_global_load_lds((as1_void*)gA[k], (as3_void*)lA[k], 16, 0, 0);
            __builtin_amdgcn_global_load_lds((as1_void*)gB[k], (as3_void*)lB[k], 16, 0, 0);
            gA[k] += 64; gB[k] += 64;
        }
        __syncthreads();

#pragma unroll
        for (int kk = 0; kk < 2; ++kk) {
            bf16x8 af[4], bfr[4];
#pragma unroll
            for (int i = 0; i < 4; ++i) {
                const int R = wm + i * 16 + mr;
                const int c8 = (kk * 4 + quad) ^ (mr & 7);
                af[i] = *(const bf16x8*)(smem + R * 64 + c8 * 8);
            }
#pragma unroll
            for (int j = 0; j < 4; ++j) {
                const int R = wn + j * 16 + mr;
                const int c8 = (kk * 4 + quad) ^ (mr & 7);
                bfr[j] = *(const bf16x8*)(smem + 8192 + R * 64 + c8 * 8);
            }
#pragma unroll
            for (int i = 0; i < 4; ++i)
#pragma unroll
                for (int j = 0; j < 4; ++j)
                    acc[i][j] = __builtin_amdgcn_mfma_f32_16x16x32_bf16(
                        af[i], bfr[j], acc[i][j], 0, 0, 0);
        }
        __syncthreads();   // after this, smem is free for epilogue reuse
    }

    // ---------------- epilogue: C/D layout col=lane&15, row=quad*4+reg -----
    if (MODE == 0) {
        // wave-private LDS transpose -> 16B fp32 stores
        float* epf = (float*)smem + wave * 2048;    // 8 KB region, uses 5120 B
#pragma unroll
        for (int j = 0; j < 4; ++j) {
            const int gcol0 = bn + wn + j * 16;
            const float bv = bias[gcol0 + mr];
#pragma unroll
            for (int i = 0; i < 4; ++i)
#pragma unroll
                for (int r = 0; r < 4; ++r)
                    epf[(i * 16 + quad * 4 + r) * 20 + mr] = acc[i][j][r] + bv;
#pragma unroll
            for (int p = 0; p < 4; ++p) {
                const int dr = p * 16 + (lane >> 2);
                const int ch = lane & 3;
                f32x4 v = *(const f32x4*)(epf + dr * 20 + ch * 4);
                *(f32x4*)(Cf + (size_t)(bm + wm + dr) * N + gcol0 + ch * 4) = v;
            }
        }
    } else if (bn < 2048) {
        // QK block: wave-private LDS transpose -> 16B bf16 stores
        unsigned short* epb = smem + wave * 4096;   // 8 KB region, uses 2560 B
#pragma unroll
        for (int j = 0; j < 4; ++j) {
            const int gcol0 = bn + wn + j * 16;
            const float bv = bias[gcol0 + mr];
#pragma unroll
            for (int i = 0; i < 4; ++i)
#pragma unroll
                for (int r = 0; r < 4; ++r)
                    epb[(i * 16 + quad * 4 + r) * 20 + mr] = f2bf(acc[i][j][r] + bv);
#pragma unroll
            for (int p = 0; p < 2; ++p) {
                const int dr = p * 32 + (lane >> 1);
                const int ch = lane & 1;
                int4v v = *(const int4v*)(epb + dr * 20 + ch * 8);
                *(int4v*)(Cb + (size_t)(bm + wm + dr) * 2048 + gcol0 + ch * 8) = v;
            }
        }
    } else {
        // V block: wave-private LDS transpose -> Vt[b][h][d][s], 8B stores
        unsigned short* ep = smem + wave * 4096;
        const int bb = (bm + wm) >> 13;
        const int ssb = (bm + wm) & 8191;
#pragma unroll
        for (int j = 0; j < 4; ++j) {
            const int gcol = bn + wn + j * 16 + mr;
            const float bv = bias[gcol];
#pragma unroll
            for (int i = 0; i < 4; ++i)
#pragma unroll
                for (int r = 0; r < 4; ++r)
                    ep[mr * 68 + i * 16 + quad * 4 + r] = f2bf(acc[i][j][r] + bv);
            const size_t vrow0 = (size_t)(bb * 1024 + (bn - 2048) + wn + j * 16);
#pragma unroll
            for (int p = 0; p < 4; ++p) {
                const int dr = (p * 64 + lane) >> 4;
                const int ch = lane & 15;
                uint2 val = *(const uint2*)(ep + dr * 68 + ch * 4);
                *(uint2*)(Vt + (vrow0 + dr) * 8192 + ssb + ch * 4) = val;
            }
        }
    }
}

__global__ __launch_bounds__(256) void gemm_qkv(
    const unsigned short* __restrict__ A, const unsigned short* __restrict__ Bt,
    const float* __restrict__ bias, unsigned short* __restrict__ Cb,
    unsigned short* __restrict__ Vt, int N, int K) {
    gemm_body<1>(A, Bt, bias, nullptr, Cb, Vt, N, K);
}

__global__ __launch_bounds__(256) void gemm_out(
    const unsigned short* __restrict__ A, const unsigned short* __restrict__ Bt,
    const float* __restrict__ bias, float* __restrict__ Cf, int N, int K) {
    gemm_body<0>(A, Bt, bias, Cf, nullptr, nullptr, N, K);
}

// --------------------------- MFMA banded attention -------------------------
// QK: (16384, 2048) bf16 rows [q(1024) k(1024)]; Vt: (2,16,64,8192) bf16.
// 1 wave = 64 consecutive queries of one (b,h). Window 96 wide, origin
// win0 = s0-8 (8-aligned -> 16B-aligned frag loads); band rel = k-m in [5,11].
__global__ __launch_bounds__(256) void attn_mfma(
    const unsigned short* __restrict__ QK, const unsigned short* __restrict__ Vt,
    unsigned short* __restrict__ out) {
    __shared__ unsigned short sP[4][64 * 104];   // 13312 B per wave
    const int tid = threadIdx.x;
    const int lane = tid & 63;
    const int wave = tid >> 6;
    const int quad = lane >> 4;
    const int cc = lane & 15;
    const int w = blockIdx.x * 4 + wave;
    const int b = w >> 11;                 // 2048 waves per batch
    const int h = (w >> 7) & 15;
    const int st = w & 127;
    const int s0 = st << 6;
    const int win0 = s0 - 8;
    const size_t tokBase = (size_t)b * 8192;
    unsigned short* P = sP[wave];

    // zero P region (13312 B = 13 x 64 lanes x 16 B)
    {
        int4v z = {0, 0, 0, 0};
#pragma unroll
        for (int i = 0; i < 13; ++i)
            *(int4v*)(P + i * 512 + lane * 8) = z;
    }

    // ---- S = Q @ K^T  (64 x 80) ----
    f32x4 accS[4][5] = {};
#pragma unroll
    for (int kc = 0; kc < 2; ++kc) {
        bf16x8 qf[4], kf[5];
#pragma unroll
        for (int mt = 0; mt < 4; ++mt)
            qf[mt] = *(const bf16x8*)(QK + (tokBase + s0 + mt * 16 + cc) * 2048
                                      + h * 64 + kc * 32 + quad * 8);
#pragma unroll
        for (int nt = 0; nt < 5; ++nt) {
            int row = win0 + nt * 16 + cc;
            row = row < 0 ? 0 : (row > 8191 ? 8191 : row);   // clamped rows masked later
            kf[nt] = *(const bf16x8*)(QK + (tokBase + row) * 2048
                                      + 1024 + h * 64 + kc * 32 + quad * 8);
        }
#pragma unroll
        for (int mt = 0; mt < 4; ++mt)
#pragma unroll
            for (int nt = 0; nt < 5; ++nt)
                accS[mt][nt] = __builtin_amdgcn_mfma_f32_16x16x32_bf16(
                    qf[mt], kf[nt], accS[mt][nt], 0, 0, 0);
    }

    // ---- band mask + softmax (normalized), P -> LDS in A-layout ----
    const float NEG = -__builtin_inff();
#pragma unroll
    for (int mt = 0; mt < 4; ++mt) {
#pragma unroll
        for (int r = 0; r < 4; ++r) {
            const int mrow = mt * 16 + quad * 4 + r;
            float v[5];
#pragma unroll
            for (int nt = 0; nt < 5; ++nt) {
                const int k = nt * 16 + cc;
                const int rel = k - mrow;
                const int sidx = win0 + k;
                const bool ok = (rel >= 5) & (rel <= 11) & (sidx >= 0) & (sidx < 8192);
                v[nt] = ok ? accS[mt][nt][r] * 0.125f : NEG;
            }
            float mx = v[0];
#pragma unroll
            for (int nt = 1; nt < 5; ++nt) mx = fmaxf(mx, v[nt]);
#pragma unroll
            for (int off = 8; off >= 1; off >>= 1) mx = fmaxf(mx, __shfl_xor(mx, off));
            float p[5], sum = 0.f;
#pragma unroll
            for (int nt = 0; nt < 5; ++nt) {
                p[nt] = __builtin_amdgcn_exp2f((v[nt] - mx) * 1.44269504f);
                sum += p[nt];
            }
#pragma unroll
            for (int off = 8; off >= 1; off >>= 1) sum += __shfl_xor(sum, off);
            const float inv = __builtin_amdgcn_rcpf(sum);
#pragma unroll
            for (int nt = 0; nt < 5; ++nt)
                P[mrow * 104 + nt * 16 + cc] = f2bf(p[nt] * inv);
        }
    }

    // ---- O = P @ V  (64 x 64), K-dim padded to 96 ----
    f32x4 accO[4][4] = {};
#pragma unroll
    for (int kc = 0; kc < 3; ++kc) {
        bf16x8 pf[4], vf[4];
#pragma unroll
        for (int mt = 0; mt < 4; ++mt)
            pf[mt] = *(const bf16x8*)(P + (mt * 16 + cc) * 104 + kc * 32 + quad * 8);
        {
            int pos = win0 + kc * 32 + quad * 8;
            pos = pos < 0 ? 0 : (pos > 8184 ? 8184 : pos);   // clamped pos hit P==0
#pragma unroll
            for (int nt = 0; nt < 4; ++nt)
                vf[nt] = *(const bf16x8*)(Vt + ((size_t)(b * 16 + h) * 64 + nt * 16 + cc) * 8192 + pos);
        }
#pragma unroll
        for (int mt = 0; mt < 4; ++mt)
#pragma unroll
            for (int nt = 0; nt < 4; ++nt)
                accO[mt][nt] = __builtin_amdgcn_mfma_f32_16x16x32_bf16(
                    pf[mt], vf[nt], accO[mt][nt], 0, 0, 0);
    }

    // ---- store: C-layout -> LDS (stride 72) -> coalesced global ----
#pragma unroll
    for (int mt = 0; mt < 4; ++mt)
#pragma unroll
        for (int nt = 0; nt < 4; ++nt)
#pragma unroll
            for (int r = 0; r < 4; ++r)
                P[(mt * 16 + quad * 4 + r) * 72 + nt * 16 + cc] = f2bf(accO[mt][nt][r]);

#pragma unroll
    for (int pass = 0; pass < 8; ++pass) {
        const int row = pass * 8 + (lane >> 3);
        const int ch = lane & 7;
        int4v vv = *(const int4v*)(P + row * 72 + ch * 8);
        *(int4v*)(out + (tokBase + s0 + row) * 1024 + h * 64 + ch * 8) = vv;
    }
}

// ------------------------------- launch ------------------------------------
extern "C" void kernel_launch(void* const* d_in, const int* in_sizes, int n_in,
                              void* d_out, int out_size, void* d_ws, size_t ws_size,
                              hipStream_t stream) {
    (void)in_sizes; (void)n_in; (void)out_size; (void)ws_size;
    const float* X  = (const float*)d_in[0];
    const float* wq = (const float*)d_in[1];
    const float* bq = (const float*)d_in[2];
    const float* wk = (const float*)d_in[3];
    const float* bk = (const float*)d_in[4];
    const float* wv = (const float*)d_in[5];
    const float* bv = (const float*)d_in[6];
    const float* wo = (const float*)d_in[7];
    const float* bo = (const float*)d_in[8];
    float* out = (float*)d_out;

    char* ws = (char*)d_ws;
    unsigned short* Xb    = (unsigned short*)(ws);                 // 32 MB
    unsigned short* WtQKV = (unsigned short*)(ws + 33554432);      // 6 MB
    unsigned short* WtO   = (unsigned short*)(ws + 39845888);      // 2 MB
    unsigned short* QK    = (unsigned short*)(ws + 41943040);      // 64 MB
    unsigned short* Vt    = (unsigned short*)(ws + 109051904);     // 32 MB
    unsigned short* AttnO = (unsigned short*)(ws + 142606336);     // 32 MB
    float*          biasQ = (float*)(ws + 176160768);              // 12 KB

    cast_kernel<<<16384, 256, 0, stream>>>(X, Xb, 4194304);
    transpose_cast4<<<dim3(32, 32, 4), 256, 0, stream>>>(wq, wk, wv, wo, WtQKV, WtO);
    concat_bias<<<12, 256, 0, stream>>>(bq, bk, bv, biasQ);

    // QKV: M=16384, N=3072, K=1024 -> QK + Vt
    gemm_qkv<<<dim3(24, 128), 256, 0, stream>>>(Xb, WtQKV, biasQ, QK, Vt, 3072, 1024);

    // attention: 4096 waves = 1024 blocks
    attn_mfma<<<1024, 256, 0, stream>>>(QK, Vt, AttnO);

    // O-proj: M=16384, N=1024, K=1024, fp32 out
    gemm_out<<<dim3(8, 128), 256, 0, stream>>>(AttnO, WtO, bo, out, 1024, 1024);
}

// Round 5
// 341.060 us; speedup vs baseline: 1.0396x; 1.0396x over previous
//
#include <hip/hip_runtime.h>

// ---------------------------------------------------------------------------
// LigerFusedNeighborhoodAttention on MI355X (gfx950)
// B=2, S=8192, H=1024, NH=16, HD=64, KERNEL=7, DILATION=1, SCALE=1/8
//
// Pipeline:
//   1. cast X fp32 -> bf16
//   2. transpose+cast weights -> bf16 (one z-indexed kernel)
//   3. fused QKV GEMM (16384 x 3072 x 1024): 256x128 block tile, 128x64
//      wave tile (MFMA-bound, not LDS-read-bound), BK=64, XOR-swizzled
//      staging, LDS-coalesced epilogues -> QK row-major + Vt (2,16,64,8192)
//   4. MFMA banded attention (unchanged, verified)
//   5. output GEMM (16384 x 1024 x 1024) -> d_out fp32
// ---------------------------------------------------------------------------

typedef __bf16 bf16x8 __attribute__((ext_vector_type(8)));
typedef float f32x4 __attribute__((ext_vector_type(4)));
typedef int int4v __attribute__((ext_vector_type(4)));
typedef __attribute__((address_space(1))) void as1_void;
typedef __attribute__((address_space(3))) void as3_void;

__device__ __forceinline__ float bf2f(unsigned short u) {
    union { unsigned int u; float f; } c;
    c.u = ((unsigned int)u) << 16;
    return c.f;
}
__device__ __forceinline__ unsigned short f2bf(float f) {
    union { float f; unsigned int u; } c;
    c.f = f;
    unsigned int u = c.u;
    u += 0x7fffu + ((u >> 16) & 1u);   // round-to-nearest-even
    return (unsigned short)(u >> 16);
}

// --------------------------- cast X fp32 -> bf16 ---------------------------
__global__ __launch_bounds__(256) void cast_kernel(
    const float* __restrict__ in, unsigned short* __restrict__ out, int n4) {
    int i = blockIdx.x * 256 + threadIdx.x;
    if (i < n4) {
        float4 v = ((const float4*)in)[i];
        ushort4 o;
        o.x = f2bf(v.x); o.y = f2bf(v.y); o.z = f2bf(v.z); o.w = f2bf(v.w);
        ((ushort4*)out)[i] = o;
    }
}

// ----------- transpose+cast 4x (1024x1024) W -> Wt bf16, z-indexed ---------
__global__ __launch_bounds__(256) void transpose_cast4(
    const float* __restrict__ w0, const float* __restrict__ w1,
    const float* __restrict__ w2, const float* __restrict__ w3,
    unsigned short* __restrict__ t0, unsigned short* __restrict__ t3) {
    __shared__ unsigned short tile[32][33];
    const int z = blockIdx.z;
    const float* W = (z == 0) ? w0 : (z == 1) ? w1 : (z == 2) ? w2 : w3;
    unsigned short* Wt = (z == 3) ? t3 : t0 + (size_t)z * 1048576;
    const int c0 = blockIdx.x * 32;
    const int r0 = blockIdx.y * 32;
    const int tx = threadIdx.x & 31;
    const int ty = threadIdx.x >> 5;
#pragma unroll
    for (int i = 0; i < 32; i += 8)
        tile[ty + i][tx] = f2bf(W[(size_t)(r0 + ty + i) * 1024 + c0 + tx]);
    __syncthreads();
#pragma unroll
    for (int i = 0; i < 32; i += 8)
        Wt[(size_t)(c0 + ty + i) * 1024 + r0 + tx] = tile[tx][ty + i];
}

// --------------------------- bias concat (3072) ----------------------------
__global__ __launch_bounds__(256) void concat_bias(
    const float* __restrict__ a, const float* __restrict__ b,
    const float* __restrict__ c, float* __restrict__ o) {
    int i = blockIdx.x * 256 + threadIdx.x;
    if (i < 3072)
        o[i] = (i < 1024) ? a[i] : ((i < 2048) ? b[i - 1024] : c[i - 2048]);
}

// ------------------------------- MFMA GEMM ---------------------------------
// C(M,N) = A(M,K)*Bt(N,K)^T + bias.  256x128 block tile, 4 waves of 128x64,
// BK=64.  Per K-iter/wave: 64 MFMA (~307 cyc) vs 24 ds_read_b128 (~288) ->
// MFMA-bound.  Staging XOR-swizzle keeps 128B-stride LDS rows conflict-free.
// MODE 0: fp32 out (16B stores).  MODE 1: QK bf16 + Vt split.
template <int MODE>
__device__ __forceinline__ void gemm_body(
    const unsigned short* __restrict__ A, const unsigned short* __restrict__ Bt,
    const float* __restrict__ bias, float* __restrict__ Cf,
    unsigned short* __restrict__ Cb, unsigned short* __restrict__ Vt,
    int N, int K) {
    __shared__ unsigned short smem[24576];   // sA = [0:16384), sB = [16384:24576)
    const int tid = threadIdx.x;
    const int lane = tid & 63;
    const int wave = tid >> 6;
    const int bm = blockIdx.y * 256;
    const int bn = blockIdx.x * 128;
    const int wm = (wave >> 1) * 128;
    const int wn = (wave & 1) * 64;
    const int quad = lane >> 4;
    const int mr = lane & 15;

    // A staging: 2048 16B chunks (256 rows x 8), thread covers 8; B: 1024/4.
    const unsigned short* gA[8];
    const unsigned short* gB[4];
    char* lA[8];
    char* lB[4];
#pragma unroll
    for (int k = 0; k < 8; ++k) {
        const int q = (k * 4 + wave) * 64 + lane;
        const int row = q >> 3;
        const int c8 = (q & 7) ^ (row & 7);          // source-column swizzle
        gA[k] = A + (size_t)(bm + row) * K + c8 * 8;
        lA[k] = (char*)smem + (size_t)(k * 4 + wave) * 1024;
    }
#pragma unroll
    for (int k = 0; k < 4; ++k) {
        const int q = (k * 4 + wave) * 64 + lane;
        const int row = q >> 3;
        const int c8 = (q & 7) ^ (row & 7);
        gB[k] = Bt + (size_t)(bn + row) * K + c8 * 8;
        lB[k] = (char*)smem + 32768 + (size_t)(k * 4 + wave) * 1024;
    }

    f32x4 acc[8][4] = {};

    for (int kt = 0; kt < K; kt += 64) {
#pragma unroll
        for (int k = 0; k < 8; ++k) {
            __builtin_amdgcn_global_load_lds((as1_void*)gA[k], (as3_void*)lA[k], 16, 0, 0);
            gA[k] += 64;
        }
#pragma unroll
        for (int k = 0; k < 4; ++k) {
            __builtin_amdgcn_global_load_lds((as1_void*)gB[k], (as3_void*)lB[k], 16, 0, 0);
            gB[k] += 64;
        }
        __syncthreads();

#pragma unroll
        for (int kk = 0; kk < 2; ++kk) {
            const int c8 = (kk * 4 + quad) ^ (mr & 7);
            bf16x8 af[8], bfr[4];
#pragma unroll
            for (int i = 0; i < 8; ++i)
                af[i] = *(const bf16x8*)(smem + (wm + i * 16 + mr) * 64 + c8 * 8);
#pragma unroll
            for (int j = 0; j < 4; ++j)
                bfr[j] = *(const bf16x8*)(smem + 16384 + (wn + j * 16 + mr) * 64 + c8 * 8);
#pragma unroll
            for (int i = 0; i < 8; ++i)
#pragma unroll
                for (int j = 0; j < 4; ++j)
                    acc[i][j] = __builtin_amdgcn_mfma_f32_16x16x32_bf16(
                        af[i], bfr[j], acc[i][j], 0, 0, 0);
        }
        __syncthreads();   // after last iter, smem is free for epilogue
    }

    // ---------------- epilogue: C/D layout col=lane&15, row=quad*4+reg -----
    unsigned short* ep = smem + wave * 4096;   // 8 KB wave-private region
    if (MODE == 0) {
        float* epf = (float*)ep;               // 64 rows x stride 20 fp32
#pragma unroll
        for (int j = 0; j < 4; ++j) {
            const int gcol0 = bn + wn + j * 16;
            const float bv = bias[gcol0 + mr];
#pragma unroll
            for (int h2 = 0; h2 < 2; ++h2) {
#pragma unroll
                for (int i2 = 0; i2 < 4; ++i2)
#pragma unroll
                    for (int r = 0; r < 4; ++r)
                        epf[(i2 * 16 + quad * 4 + r) * 20 + mr] = acc[h2 * 4 + i2][j][r] + bv;
#pragma unroll
                for (int p = 0; p < 4; ++p) {
                    const int dr = p * 16 + (lane >> 2);
                    const int ch = lane & 3;
                    f32x4 v = *(const f32x4*)(epf + dr * 20 + ch * 4);
                    *(f32x4*)(Cf + (size_t)(bm + wm + h2 * 64 + dr) * N + gcol0 + ch * 4) = v;
                }
            }
        }
    } else if (bn < 2048) {
        // QK block: 128 rows x stride 20 bf16 -> 16B stores
#pragma unroll
        for (int j = 0; j < 4; ++j) {
            const int gcol0 = bn + wn + j * 16;
            const float bv = bias[gcol0 + mr];
#pragma unroll
            for (int i = 0; i < 8; ++i)
#pragma unroll
                for (int r = 0; r < 4; ++r)
                    ep[(i * 16 + quad * 4 + r) * 20 + mr] = f2bf(acc[i][j][r] + bv);
#pragma unroll
            for (int p = 0; p < 4; ++p) {
                const int dr = p * 32 + (lane >> 1);
                const int ch = lane & 1;
                int4v v = *(const int4v*)(ep + dr * 20 + ch * 8);
                *(int4v*)(Cb + (size_t)(bm + wm + dr) * 2048 + gcol0 + ch * 8) = v;
            }
        }
    } else {
        // V block: transpose to Vt[b][h][d][s]; 16 d-rows x 128 s, 16B stores
        const int bb = (bm + wm) >> 13;
        const int ssb = (bm + wm) & 8191;
#pragma unroll
        for (int j = 0; j < 4; ++j) {
            const int gcol = bn + wn + j * 16 + mr;
            const float bv = bias[gcol];
#pragma unroll
            for (int i = 0; i < 8; ++i)
#pragma unroll
                for (int r = 0; r < 4; ++r)
                    ep[mr * 132 + i * 16 + quad * 4 + r] = f2bf(acc[i][j][r] + bv);
            const size_t vrow0 = (size_t)(bb * 1024 + (bn - 2048) + wn + j * 16);
#pragma unroll
            for (int p = 0; p < 4; ++p) {
                const int dr = p * 4 + (lane >> 4);
                const int ch = lane & 15;
                int4v v = *(const int4v*)(ep + dr * 132 + ch * 8);
                *(int4v*)(Vt + (vrow0 + dr) * 8192 + ssb + ch * 8) = v;
            }
        }
    }
}

__global__ __launch_bounds__(256, 2) void gemm_qkv(
    const unsigned short* __restrict__ A, const unsigned short* __restrict__ Bt,
    const float* __restrict__ bias, unsigned short* __restrict__ Cb,
    unsigned short* __restrict__ Vt, int N, int K) {
    gemm_body<1>(A, Bt, bias, nullptr, Cb, Vt, N, K);
}

__global__ __launch_bounds__(256, 2) void gemm_out(
    const unsigned short* __restrict__ A, const unsigned short* __restrict__ Bt,
    const float* __restrict__ bias, float* __restrict__ Cf, int N, int K) {
    gemm_body<0>(A, Bt, bias, Cf, nullptr, nullptr, N, K);
}

// --------------------------- MFMA banded attention -------------------------
// QK: (16384, 2048) bf16 rows [q(1024) k(1024)]; Vt: (2,16,64,8192) bf16.
// 1 wave = 64 consecutive queries of one (b,h). Window 96 wide, origin
// win0 = s0-8 (8-aligned -> 16B-aligned frag loads); band rel = k-m in [5,11].
__global__ __launch_bounds__(256) void attn_mfma(
    const unsigned short* __restrict__ QK, const unsigned short* __restrict__ Vt,
    unsigned short* __restrict__ out) {
    __shared__ unsigned short sP[4][64 * 104];   // 13312 B per wave
    const int tid = threadIdx.x;
    const int lane = tid & 63;
    const int wave = tid >> 6;
    const int quad = lane >> 4;
    const int cc = lane & 15;
    const int w = blockIdx.x * 4 + wave;
    const int b = w >> 11;                 // 2048 waves per batch
    const int h = (w >> 7) & 15;
    const int st = w & 127;
    const int s0 = st << 6;
    const int win0 = s0 - 8;
    const size_t tokBase = (size_t)b * 8192;
    unsigned short* P = sP[wave];

    // zero P region (13312 B = 13 x 64 lanes x 16 B)
    {
        int4v z = {0, 0, 0, 0};
#pragma unroll
        for (int i = 0; i < 13; ++i)
            *(int4v*)(P + i * 512 + lane * 8) = z;
    }

    // ---- S = Q @ K^T  (64 x 80) ----
    f32x4 accS[4][5] = {};
#pragma unroll
    for (int kc = 0; kc < 2; ++kc) {
        bf16x8 qf[4], kf[5];
#pragma unroll
        for (int mt = 0; mt < 4; ++mt)
            qf[mt] = *(const bf16x8*)(QK + (tokBase + s0 + mt * 16 + cc) * 2048
                                      + h * 64 + kc * 32 + quad * 8);
#pragma unroll
        for (int nt = 0; nt < 5; ++nt) {
            int row = win0 + nt * 16 + cc;
            row = row < 0 ? 0 : (row > 8191 ? 8191 : row);   // clamped rows masked later
            kf[nt] = *(const bf16x8*)(QK + (tokBase + row) * 2048
                                      + 1024 + h * 64 + kc * 32 + quad * 8);
        }
#pragma unroll
        for (int mt = 0; mt < 4; ++mt)
#pragma unroll
            for (int nt = 0; nt < 5; ++nt)
                accS[mt][nt] = __builtin_amdgcn_mfma_f32_16x16x32_bf16(
                    qf[mt], kf[nt], accS[mt][nt], 0, 0, 0);
    }

    // ---- band mask + softmax (normalized), P -> LDS in A-layout ----
    const float NEG = -__builtin_inff();
#pragma unroll
    for (int mt = 0; mt < 4; ++mt) {
#pragma unroll
        for (int r = 0; r < 4; ++r) {
            const int mrow = mt * 16 + quad * 4 + r;
            float v[5];
#pragma unroll
            for (int nt = 0; nt < 5; ++nt) {
                const int k = nt * 16 + cc;
                const int rel = k - mrow;
                const int sidx = win0 + k;
                const bool ok = (rel >= 5) & (rel <= 11) & (sidx >= 0) & (sidx < 8192);
                v[nt] = ok ? accS[mt][nt][r] * 0.125f : NEG;
            }
            float mx = v[0];
#pragma unroll
            for (int nt = 1; nt < 5; ++nt) mx = fmaxf(mx, v[nt]);
#pragma unroll
            for (int off = 8; off >= 1; off >>= 1) mx = fmaxf(mx, __shfl_xor(mx, off));
            float p[5], sum = 0.f;
#pragma unroll
            for (int nt = 0; nt < 5; ++nt) {
                p[nt] = __builtin_amdgcn_exp2f((v[nt] - mx) * 1.44269504f);
                sum += p[nt];
            }
#pragma unroll
            for (int off = 8; off >= 1; off >>= 1) sum += __shfl_xor(sum, off);
            const float inv = __builtin_amdgcn_rcpf(sum);
#pragma unroll
            for (int nt = 0; nt < 5; ++nt)
                P[mrow * 104 + nt * 16 + cc] = f2bf(p[nt] * inv);
        }
    }

    // ---- O = P @ V  (64 x 64), K-dim padded to 96 ----
    f32x4 accO[4][4] = {};
#pragma unroll
    for (int kc = 0; kc < 3; ++kc) {
        bf16x8 pf[4], vf[4];
#pragma unroll
        for (int mt = 0; mt < 4; ++mt)
            pf[mt] = *(const bf16x8*)(P + (mt * 16 + cc) * 104 + kc * 32 + quad * 8);
        {
            int pos = win0 + kc * 32 + quad * 8;
            pos = pos < 0 ? 0 : (pos > 8184 ? 8184 : pos);   // clamped pos hit P==0
#pragma unroll
            for (int nt = 0; nt < 4; ++nt)
                vf[nt] = *(const bf16x8*)(Vt + ((size_t)(b * 16 + h) * 64 + nt * 16 + cc) * 8192 + pos);
        }
#pragma unroll
        for (int mt = 0; mt < 4; ++mt)
#pragma unroll
            for (int nt = 0; nt < 4; ++nt)
                accO[mt][nt] = __builtin_amdgcn_mfma_f32_16x16x32_bf16(
                    pf[mt], vf[nt], accO[mt][nt], 0, 0, 0);
    }

    // ---- store: C-layout -> LDS (stride 72) -> coalesced global ----
#pragma unroll
    for (int mt = 0; mt < 4; ++mt)
#pragma unroll
        for (int nt = 0; nt < 4; ++nt)
#pragma unroll
            for (int r = 0; r < 4; ++r)
                P[(mt * 16 + quad * 4 + r) * 72 + nt * 16 + cc] = f2bf(accO[mt][nt][r]);

#pragma unroll
    for (int pass = 0; pass < 8; ++pass) {
        const int row = pass * 8 + (lane >> 3);
        const int ch = lane & 7;
        int4v vv = *(const int4v*)(P + row * 72 + ch * 8);
        *(int4v*)(out + (tokBase + s0 + row) * 1024 + h * 64 + ch * 8) = vv;
    }
}

// ------------------------------- launch ------------------------------------
extern "C" void kernel_launch(void* const* d_in, const int* in_sizes, int n_in,
                              void* d_out, int out_size, void* d_ws, size_t ws_size,
                              hipStream_t stream) {
    (void)in_sizes; (void)n_in; (void)out_size; (void)ws_size;
    const float* X  = (const float*)d_in[0];
    const float* wq = (const float*)d_in[1];
    const float* bq = (const float*)d_in[2];
    const float* wk = (const float*)d_in[3];
    const float* bk = (const float*)d_in[4];
    const float* wv = (const float*)d_in[5];
    const float* bv = (const float*)d_in[6];
    const float* wo = (const float*)d_in[7];
    const float* bo = (const float*)d_in[8];
    float* out = (float*)d_out;

    char* ws = (char*)d_ws;
    unsigned short* Xb    = (unsigned short*)(ws);                 // 32 MB
    unsigned short* WtQKV = (unsigned short*)(ws + 33554432);      // 6 MB
    unsigned short* WtO   = (unsigned short*)(ws + 39845888);      // 2 MB
    unsigned short* QK    = (unsigned short*)(ws + 41943040);      // 64 MB
    unsigned short* Vt    = (unsigned short*)(ws + 109051904);     // 32 MB
    unsigned short* AttnO = (unsigned short*)(ws + 142606336);     // 32 MB
    float*          biasQ = (float*)(ws + 176160768);              // 12 KB

    cast_kernel<<<16384, 256, 0, stream>>>(X, Xb, 4194304);
    transpose_cast4<<<dim3(32, 32, 4), 256, 0, stream>>>(wq, wk, wv, wo, WtQKV, WtO);
    concat_bias<<<12, 256, 0, stream>>>(bq, bk, bv, biasQ);

    // QKV: M=16384, N=3072, K=1024 -> QK + Vt   (256-row x 128-col tiles)
    gemm_qkv<<<dim3(24, 64), 256, 0, stream>>>(Xb, WtQKV, biasQ, QK, Vt, 3072, 1024);

    // attention: 4096 waves = 1024 blocks
    attn_mfma<<<1024, 256, 0, stream>>>(QK, Vt, AttnO);

    // O-proj: M=16384, N=1024, K=1024, fp32 out
    gemm_out<<<dim3(8, 64), 256, 0, stream>>>(AttnO, WtO, bo, out, 1024, 1024);
}

// Round 7
// 332.171 us; speedup vs baseline: 1.0674x; 1.0268x over previous
//
#include <hip/hip_runtime.h>

// ---------------------------------------------------------------------------
// LigerFusedNeighborhoodAttention on MI355X (gfx950)
// B=2, S=8192, H=1024, NH=16, HD=64, KERNEL=7, DILATION=1, SCALE=1/8
//
// Pipeline (4 launches):
//   1. prep: cast X fp32->bf16 + transpose 4 weights + bias concat (fused)
//   2. fused QKV GEMM (16384 x 3072 x 1024): 256x128 tile (MT=8), BK=64,
//      XOR-swizzled staging -> QK row-major + Vt (2,16,64,8192)
//   3. MFMA banded attention (verified)
//   4. output GEMM (16384 x 1024 x 1024): 128x128 tile (MT=4, 1024 blocks,
//      4 blk/CU) -> d_out fp32
// LDS layout (gemm): A = MT*2048 shorts, B = 8192 shorts at +MT*4096 bytes.
// ---------------------------------------------------------------------------

typedef __bf16 bf16x8 __attribute__((ext_vector_type(8)));
typedef float f32x4 __attribute__((ext_vector_type(4)));
typedef int int4v __attribute__((ext_vector_type(4)));
typedef __attribute__((address_space(1))) void as1_void;
typedef __attribute__((address_space(3))) void as3_void;

__device__ __forceinline__ float bf2f(unsigned short u) {
    union { unsigned int u; float f; } c;
    c.u = ((unsigned int)u) << 16;
    return c.f;
}
__device__ __forceinline__ unsigned short f2bf(float f) {
    union { float f; unsigned int u; } c;
    c.f = f;
    unsigned int u = c.u;
    u += 0x7fffu + ((u >> 16) & 1u);   // round-to-nearest-even
    return (unsigned short)(u >> 16);
}

// ------------- prep: cast X + transpose 4 weights + concat bias ------------
// grid.x = 16384 (cast) + 4096 (transpose) + 12 (bias) = 20492
__global__ __launch_bounds__(256) void prep(
    const float* __restrict__ X, const float* __restrict__ w0,
    const float* __restrict__ w1, const float* __restrict__ w2,
    const float* __restrict__ w3, const float* __restrict__ bq,
    const float* __restrict__ bk, const float* __restrict__ bv,
    unsigned short* __restrict__ Xb, unsigned short* __restrict__ t0,
    unsigned short* __restrict__ t3, float* __restrict__ biasQ) {
    __shared__ unsigned short tile[32][33];
    const int bid = blockIdx.x;
    if (bid < 16384) {
        int i = bid * 256 + threadIdx.x;
        float4 v = ((const float4*)X)[i];
        ushort4 o;
        o.x = f2bf(v.x); o.y = f2bf(v.y); o.z = f2bf(v.z); o.w = f2bf(v.w);
        ((ushort4*)Xb)[i] = o;
    } else if (bid < 20480) {
        const int t = bid - 16384;
        const int z = t >> 10;
        const int rem = t & 1023;
        const float* W = (z == 0) ? w0 : (z == 1) ? w1 : (z == 2) ? w2 : w3;
        unsigned short* Wt = (z == 3) ? t3 : t0 + (size_t)z * 1048576;
        const int c0 = (rem & 31) * 32;
        const int r0 = (rem >> 5) * 32;
        const int tx = threadIdx.x & 31;
        const int ty = threadIdx.x >> 5;
#pragma unroll
        for (int i = 0; i < 32; i += 8)
            tile[ty + i][tx] = f2bf(W[(size_t)(r0 + ty + i) * 1024 + c0 + tx]);
        __syncthreads();
#pragma unroll
        for (int i = 0; i < 32; i += 8)
            Wt[(size_t)(c0 + ty + i) * 1024 + r0 + tx] = tile[tx][ty + i];
    } else {
        int i = (bid - 20480) * 256 + threadIdx.x;
        if (i < 3072)
            biasQ[i] = (i < 1024) ? bq[i] : ((i < 2048) ? bk[i - 1024] : bv[i - 2048]);
    }
}

// ------------------------------- MFMA GEMM ---------------------------------
// C(M,N) = A(M,K)*Bt(N,K)^T + bias.  Block tile (MT*32) x 128, 4 waves of
// (MT*16) x 64, BK=64.  XOR-swizzled staging: conflict-free 128B-stride LDS.
// MODE 0: fp32 out (16B stores).  MODE 1: QK bf16 + Vt split (MT=8 only).
template <int MODE, int MT>
__device__ __forceinline__ void gemm_body(
    const unsigned short* __restrict__ A, const unsigned short* __restrict__ Bt,
    const float* __restrict__ bias, float* __restrict__ Cf,
    unsigned short* __restrict__ Cb, unsigned short* __restrict__ Vt,
    int N, int K) {
    // A region: MT*2048 shorts (MT*32 rows x 64); B region: 8192 shorts.
    __shared__ unsigned short smem[MT * 2048 + 8192];
    const int tid = threadIdx.x;
    const int lane = tid & 63;
    const int wave = tid >> 6;
    const int bm = blockIdx.y * (MT * 32);
    const int bn = blockIdx.x * 128;
    const int wm = (wave >> 1) * (MT * 16);
    const int wn = (wave & 1) * 64;
    const int quad = lane >> 4;
    const int mr = lane & 15;

    const unsigned short* gA[MT];
    const unsigned short* gB[4];
    char* lA[MT];
    char* lB[4];
#pragma unroll
    for (int k = 0; k < MT; ++k) {
        const int q = (k * 4 + wave) * 64 + lane;
        const int row = q >> 3;
        const int c8 = (q & 7) ^ (row & 7);          // source-column swizzle
        gA[k] = A + (size_t)(bm + row) * K + c8 * 8;
        lA[k] = (char*)smem + (size_t)(k * 4 + wave) * 1024;
    }
#pragma unroll
    for (int k = 0; k < 4; ++k) {
        const int q = (k * 4 + wave) * 64 + lane;
        const int row = q >> 3;
        const int c8 = (q & 7) ^ (row & 7);
        gB[k] = Bt + (size_t)(bn + row) * K + c8 * 8;
        lB[k] = (char*)smem + (size_t)MT * 4096 + (size_t)(k * 4 + wave) * 1024;
    }

    f32x4 acc[MT][4] = {};

    for (int kt = 0; kt < K; kt += 64) {
#pragma unroll
        for (int k = 0; k < MT; ++k) {
            __builtin_amdgcn_global_load_lds((as1_void*)gA[k], (as3_void*)lA[k], 16, 0, 0);
            gA[k] += 64;
        }
#pragma unroll
        for (int k = 0; k < 4; ++k) {
            __builtin_amdgcn_global_load_lds((as1_void*)gB[k], (as3_void*)lB[k], 16, 0, 0);
            gB[k] += 64;
        }
        __syncthreads();

#pragma unroll
        for (int kk = 0; kk < 2; ++kk) {
            const int c8 = (kk * 4 + quad) ^ (mr & 7);
            bf16x8 af[MT], bfr[4];
#pragma unroll
            for (int i = 0; i < MT; ++i)
                af[i] = *(const bf16x8*)(smem + (wm + i * 16 + mr) * 64 + c8 * 8);
#pragma unroll
            for (int j = 0; j < 4; ++j)
                bfr[j] = *(const bf16x8*)(smem + MT * 2048 + (wn + j * 16 + mr) * 64 + c8 * 8);
#pragma unroll
            for (int i = 0; i < MT; ++i)
#pragma unroll
                for (int j = 0; j < 4; ++j)
                    acc[i][j] = __builtin_amdgcn_mfma_f32_16x16x32_bf16(
                        af[i], bfr[j], acc[i][j], 0, 0, 0);
        }
        __syncthreads();   // after last iter, smem is free for epilogue
    }

    // ---------------- epilogue: C/D layout col=lane&15, row=quad*4+reg -----
    if (MODE == 0) {
        float* epf = (float*)smem + wave * 1280;   // 5120 B per wave
#pragma unroll
        for (int j = 0; j < 4; ++j) {
            const int gcol0 = bn + wn + j * 16;
            const float bv = bias[gcol0 + mr];
#pragma unroll
            for (int h2 = 0; h2 < MT / 4; ++h2) {
#pragma unroll
                for (int i2 = 0; i2 < 4; ++i2)
#pragma unroll
                    for (int r = 0; r < 4; ++r)
                        epf[(i2 * 16 + quad * 4 + r) * 20 + mr] = acc[h2 * 4 + i2][j][r] + bv;
#pragma unroll
                for (int p = 0; p < 4; ++p) {
                    const int dr = p * 16 + (lane >> 2);
                    const int ch = lane & 3;
                    f32x4 v = *(const f32x4*)(epf + dr * 20 + ch * 4);
                    *(f32x4*)(Cf + (size_t)(bm + wm + h2 * 64 + dr) * N + gcol0 + ch * 4) = v;
                }
            }
        }
    } else if (bn < 2048) {
        // QK block (MT=8): 128 rows x stride 20 bf16 -> 16B stores
        unsigned short* ep = smem + wave * 4096;   // 8 KB per wave
#pragma unroll
        for (int j = 0; j < 4; ++j) {
            const int gcol0 = bn + wn + j * 16;
            const float bv = bias[gcol0 + mr];
#pragma unroll
            for (int i = 0; i < MT; ++i)
#pragma unroll
                for (int r = 0; r < 4; ++r)
                    ep[(i * 16 + quad * 4 + r) * 20 + mr] = f2bf(acc[i][j][r] + bv);
#pragma unroll
            for (int p = 0; p < MT / 2; ++p) {
                const int dr = p * 32 + (lane >> 1);
                const int ch = lane & 1;
                int4v v = *(const int4v*)(ep + dr * 20 + ch * 8);
                *(int4v*)(Cb + (size_t)(bm + wm + dr) * 2048 + gcol0 + ch * 8) = v;
            }
        }
    } else {
        // V block (MT=8): transpose to Vt[b][h][d][s]; 16B stores
        unsigned short* ep = smem + wave * 4096;
        const int bb = (bm + wm) >> 13;
        const int ssb = (bm + wm) & 8191;
#pragma unroll
        for (int j = 0; j < 4; ++j) {
            const int gcol = bn + wn + j * 16 + mr;
            const float bv = bias[gcol];
#pragma unroll
            for (int i = 0; i < MT; ++i)
#pragma unroll
                for (int r = 0; r < 4; ++r)
                    ep[mr * 132 + i * 16 + quad * 4 + r] = f2bf(acc[i][j][r] + bv);
            const size_t vrow0 = (size_t)(bb * 1024 + (bn - 2048) + wn + j * 16);
#pragma unroll
            for (int p = 0; p < 4; ++p) {
                const int dr = p * 4 + (lane >> 4);
                const int ch = lane & 15;
                int4v v = *(const int4v*)(ep + dr * 132 + ch * 8);
                *(int4v*)(Vt + (vrow0 + dr) * 8192 + ssb + ch * 8) = v;
            }
        }
    }
}

__global__ __launch_bounds__(256, 2) void gemm_qkv(
    const unsigned short* __restrict__ A, const unsigned short* __restrict__ Bt,
    const float* __restrict__ bias, unsigned short* __restrict__ Cb,
    unsigned short* __restrict__ Vt, int N, int K) {
    gemm_body<1, 8>(A, Bt, bias, nullptr, Cb, Vt, N, K);
}

__global__ __launch_bounds__(256, 4) void gemm_out(
    const unsigned short* __restrict__ A, const unsigned short* __restrict__ Bt,
    const float* __restrict__ bias, float* __restrict__ Cf, int N, int K) {
    gemm_body<0, 4>(A, Bt, bias, Cf, nullptr, nullptr, N, K);
}

// --------------------------- MFMA banded attention -------------------------
// QK: (16384, 2048) bf16 rows [q(1024) k(1024)]; Vt: (2,16,64,8192) bf16.
// 1 wave = 64 consecutive queries of one (b,h). Window 96 wide, origin
// win0 = s0-8 (8-aligned -> 16B-aligned frag loads); band rel = k-m in [5,11].
__global__ __launch_bounds__(256) void attn_mfma(
    const unsigned short* __restrict__ QK, const unsigned short* __restrict__ Vt,
    unsigned short* __restrict__ out) {
    __shared__ unsigned short sP[4][64 * 104];   // 13312 B per wave
    const int tid = threadIdx.x;
    const int lane = tid & 63;
    const int wave = tid >> 6;
    const int quad = lane >> 4;
    const int cc = lane & 15;
    const int w = blockIdx.x * 4 + wave;
    const int b = w >> 11;                 // 2048 waves per batch
    const int h = (w >> 7) & 15;
    const int st = w & 127;
    const int s0 = st << 6;
    const int win0 = s0 - 8;
    const size_t tokBase = (size_t)b * 8192;
    unsigned short* P = sP[wave];

    // zero P region (13312 B = 13 x 64 lanes x 16 B)
    {
        int4v z = {0, 0, 0, 0};
#pragma unroll
        for (int i = 0; i < 13; ++i)
            *(int4v*)(P + i * 512 + lane * 8) = z;
    }

    // ---- S = Q @ K^T  (64 x 80) ----
    f32x4 accS[4][5] = {};
#pragma unroll
    for (int kc = 0; kc < 2; ++kc) {
        bf16x8 qf[4], kf[5];
#pragma unroll
        for (int mt = 0; mt < 4; ++mt)
            qf[mt] = *(const bf16x8*)(QK + (tokBase + s0 + mt * 16 + cc) * 2048
                                      + h * 64 + kc * 32 + quad * 8);
#pragma unroll
        for (int nt = 0; nt < 5; ++nt) {
            int row = win0 + nt * 16 + cc;
            row = row < 0 ? 0 : (row > 8191 ? 8191 : row);   // clamped rows masked later
            kf[nt] = *(const bf16x8*)(QK + (tokBase + row) * 2048
                                      + 1024 + h * 64 + kc * 32 + quad * 8);
        }
#pragma unroll
        for (int mt = 0; mt < 4; ++mt)
#pragma unroll
            for (int nt = 0; nt < 5; ++nt)
                accS[mt][nt] = __builtin_amdgcn_mfma_f32_16x16x32_bf16(
                    qf[mt], kf[nt], accS[mt][nt], 0, 0, 0);
    }

    // ---- band mask + softmax (normalized), P -> LDS in A-layout ----
    const float NEG = -__builtin_inff();
#pragma unroll
    for (int mt = 0; mt < 4; ++mt) {
#pragma unroll
        for (int r = 0; r < 4; ++r) {
            const int mrow = mt * 16 + quad * 4 + r;
            float v[5];
#pragma unroll
            for (int nt = 0; nt < 5; ++nt) {
                const int k = nt * 16 + cc;
                const int rel = k - mrow;
                const int sidx = win0 + k;
                const bool ok = (rel >= 5) & (rel <= 11) & (sidx >= 0) & (sidx < 8192);
                v[nt] = ok ? accS[mt][nt][r] * 0.125f : NEG;
            }
            float mx = v[0];
#pragma unroll
            for (int nt = 1; nt < 5; ++nt) mx = fmaxf(mx, v[nt]);
#pragma unroll
            for (int off = 8; off >= 1; off >>= 1) mx = fmaxf(mx, __shfl_xor(mx, off));
            float p[5], sum = 0.f;
#pragma unroll
            for (int nt = 0; nt < 5; ++nt) {
                p[nt] = __builtin_amdgcn_exp2f((v[nt] - mx) * 1.44269504f);
                sum += p[nt];
            }
#pragma unroll
            for (int off = 8; off >= 1; off >>= 1) sum += __shfl_xor(sum, off);
            const float inv = __builtin_amdgcn_rcpf(sum);
#pragma unroll
            for (int nt = 0; nt < 5; ++nt)
                P[mrow * 104 + nt * 16 + cc] = f2bf(p[nt] * inv);
        }
    }

    // ---- O = P @ V  (64 x 64), K-dim padded to 96 ----
    f32x4 accO[4][4] = {};
#pragma unroll
    for (int kc = 0; kc < 3; ++kc) {
        bf16x8 pf[4], vf[4];
#pragma unroll
        for (int mt = 0; mt < 4; ++mt)
            pf[mt] = *(const bf16x8*)(P + (mt * 16 + cc) * 104 + kc * 32 + quad * 8);
        {
            int pos = win0 + kc * 32 + quad * 8;
            pos = pos < 0 ? 0 : (pos > 8184 ? 8184 : pos);   // clamped pos hit P==0
#pragma unroll
            for (int nt = 0; nt < 4; ++nt)
                vf[nt] = *(const bf16x8*)(Vt + ((size_t)(b * 16 + h) * 64 + nt * 16 + cc) * 8192 + pos);
        }
#pragma unroll
        for (int mt = 0; mt < 4; ++mt)
#pragma unroll
            for (int nt = 0; nt < 4; ++nt)
                accO[mt][nt] = __builtin_amdgcn_mfma_f32_16x16x32_bf16(
                    pf[mt], vf[nt], accO[mt][nt], 0, 0, 0);
    }

    // ---- store: C-layout -> LDS (stride 72) -> coalesced global ----
#pragma unroll
    for (int mt = 0; mt < 4; ++mt)
#pragma unroll
        for (int nt = 0; nt < 4; ++nt)
#pragma unroll
            for (int r = 0; r < 4; ++r)
                P[(mt * 16 + quad * 4 + r) * 72 + nt * 16 + cc] = f2bf(accO[mt][nt][r]);

#pragma unroll
    for (int pass = 0; pass < 8; ++pass) {
        const int row = pass * 8 + (lane >> 3);
        const int ch = lane & 7;
        int4v vv = *(const int4v*)(P + row * 72 + ch * 8);
        *(int4v*)(out + (tokBase + s0 + row) * 1024 + h * 64 + ch * 8) = vv;
    }
}

// ------------------------------- launch ------------------------------------
extern "C" void kernel_launch(void* const* d_in, const int* in_sizes, int n_in,
                              void* d_out, int out_size, void* d_ws, size_t ws_size,
                              hipStream_t stream) {
    (void)in_sizes; (void)n_in; (void)out_size; (void)ws_size;
    const float* X  = (const float*)d_in[0];
    const float* wq = (const float*)d_in[1];
    const float* bq = (const float*)d_in[2];
    const float* wk = (const float*)d_in[3];
    const float* bk = (const float*)d_in[4];
    const float* wv = (const float*)d_in[5];
    const float* bv = (const float*)d_in[6];
    const float* wo = (const float*)d_in[7];
    const float* bo = (const float*)d_in[8];
    float* out = (float*)d_out;

    char* ws = (char*)d_ws;
    unsigned short* Xb    = (unsigned short*)(ws);                 // 32 MB
    unsigned short* WtQKV = (unsigned short*)(ws + 33554432);      // 6 MB
    unsigned short* WtO   = (unsigned short*)(ws + 39845888);      // 2 MB
    unsigned short* QK    = (unsigned short*)(ws + 41943040);      // 64 MB
    unsigned short* Vt    = (unsigned short*)(ws + 109051904);     // 32 MB
    unsigned short* AttnO = (unsigned short*)(ws + 142606336);     // 32 MB
    float*          biasQ = (float*)(ws + 176160768);              // 12 KB

    prep<<<20492, 256, 0, stream>>>(X, wq, wk, wv, wo, bq, bk, bv,
                                    Xb, WtQKV, WtO, biasQ);

    // QKV: M=16384, N=3072, K=1024 -> QK + Vt   (256-row x 128-col tiles)
    gemm_qkv<<<dim3(24, 64), 256, 0, stream>>>(Xb, WtQKV, biasQ, QK, Vt, 3072, 1024);

    // attention: 4096 waves = 1024 blocks
    attn_mfma<<<1024, 256, 0, stream>>>(QK, Vt, AttnO);

    // O-proj: M=16384, N=1024, K=1024, fp32 out  (128x128 tiles, 1024 blocks)
    gemm_out<<<dim3(8, 128), 256, 0, stream>>>(AttnO, WtO, bo, out, 1024, 1024);
}